// Round 11
// baseline (218.316 us; speedup 1.0000x reference)
//
#include <hip/hip_runtime.h>
#include <hip/hip_fp16.h>

#define NN 50000
#define EE 800000
#define ELL (EE + NN)
#define NSLICE 8
#define SLICE_W (NN / NSLICE)   // 6250, exact

__device__ __forceinline__ int edge_at(const void* ei, int is64, long long idx) {
  if (is64) return (int)((const long long*)ei)[idx];
  return ((const int*)ei)[idx];
}

__device__ __forceinline__ float leaky(float x) { return x > 0.f ? x : 0.2f * x; }

// ---------------------------------------------------------------------------
// zero + edge-dtype probe fused (block 0 / thread 0 does the probe).
// int64 little-endian with values < 2^31  =>  odd 32-bit words are all zero.
// ---------------------------------------------------------------------------

__global__ void __launch_bounds__(256) zero_detect_kernel(int* __restrict__ p, int n,
                                                          const unsigned* __restrict__ ei_words,
                                                          int* __restrict__ flag) {
  if (blockIdx.x == 0 && threadIdx.x == 0) {
    unsigned acc = 0;
    for (int i = 1; i < 64; i += 2) acc |= ei_words[i];
    *flag = (acc == 0u) ? 1 : 0;
  }
  int stride = gridDim.x * blockDim.x;
  for (int i = blockIdx.x * blockDim.x + threadIdx.x; i < n; i += stride) p[i] = 0;
}

// ---------------------------------------------------------------------------
// CSR build, XCD-sliced (family f = blockIdx&7 owns dst slice f): cnt/cursor/
// srcs_sorted regions are single-XCD -> no cross-XCD line ping-pong (r8 fix).
// ---------------------------------------------------------------------------

__global__ void __launch_bounds__(256) count_kernel(const void* __restrict__ ei,
                                                    const int* __restrict__ flag,
                                                    int* __restrict__ cnt) {
  int is64 = *flag;
  int fam = blockIdx.x & (NSLICE - 1);
  int bf = blockIdx.x >> 3;
  int nf = gridDim.x >> 3;
  int lo = fam * SLICE_W, hi = lo + SLICE_W;
  for (int i = bf * blockDim.x + threadIdx.x; i < ELL; i += nf * blockDim.x) {
    int d = (i < EE) ? edge_at(ei, is64, (long long)EE + i) : (i - EE);
    if (d >= lo && d < hi) atomicAdd(&cnt[d], 1);
  }
}

__global__ void __launch_bounds__(256) scan1_kernel(const int* __restrict__ cnt,
                                                    int* __restrict__ excl,
                                                    int* __restrict__ bsum) {
  __shared__ int sh[256];
  int t = threadIdx.x;
  int base = blockIdx.x * 1024 + t * 4;
  int v0 = 0, v1 = 0, v2 = 0, v3 = 0;
  if (base + 0 < NN) v0 = cnt[base + 0];
  if (base + 1 < NN) v1 = cnt[base + 1];
  if (base + 2 < NN) v2 = cnt[base + 2];
  if (base + 3 < NN) v3 = cnt[base + 3];
  int s = v0 + v1 + v2 + v3;
  sh[t] = s;
  __syncthreads();
  for (int off = 1; off < 256; off <<= 1) {
    int x = (t >= off) ? sh[t - off] : 0;
    __syncthreads();
    sh[t] += x;
    __syncthreads();
  }
  if (t == 255) bsum[blockIdx.x] = sh[255];
  int run = sh[t] - s;
  if (base + 0 < NN) excl[base + 0] = run;
  run += v0;
  if (base + 1 < NN) excl[base + 1] = run;
  run += v1;
  if (base + 2 < NN) excl[base + 2] = run;
  run += v2;
  if (base + 3 < NN) excl[base + 3] = run;
}

__global__ void scan2_kernel(int* __restrict__ bsum, int nb) {
  if (threadIdx.x == 0 && blockIdx.x == 0) {
    int run = 0;
    for (int i = 0; i < nb; ++i) { int x = bsum[i]; bsum[i] = run; run += x; }
    bsum[nb] = run;
  }
}

__global__ void __launch_bounds__(256) scan3_kernel(int* __restrict__ row_ptr,
                                                    const int* __restrict__ bsum,
                                                    int nb) {
  int i = blockIdx.x * blockDim.x + threadIdx.x;
  if (i < NN) row_ptr[i] += bsum[i >> 10];
  if (i == 0) row_ptr[NN] = bsum[nb];
}

// Scatter + layer-1 edge-weight precompute (runs AFTER gemm1, which produces
// asrc1/adst1). Writes per-edge fp16 weights for all 4 heads at w1h[pos*4],
// position-aligned with srcs_sorted -> agg1's inner loop needs NO dependent
// asrc gather and NO exp (shortens the latency chain to one gather).
__global__ void __launch_bounds__(256) scatter_kernel(const void* __restrict__ ei,
                                                      const int* __restrict__ flag,
                                                      const int* __restrict__ row_ptr,
                                                      int* __restrict__ cursor,
                                                      int* __restrict__ srcs_sorted,
                                                      const float* __restrict__ asrc,
                                                      const float* __restrict__ adst,
                                                      __half* __restrict__ w1h) {
  int is64 = *flag;
  int fam = blockIdx.x & (NSLICE - 1);
  int bf = blockIdx.x >> 3;
  int nf = gridDim.x >> 3;
  int lo = fam * SLICE_W, hi = lo + SLICE_W;
  for (int i = bf * blockDim.x + threadIdx.x; i < ELL; i += nf * blockDim.x) {
    int s, d;
    if (i < EE) {
      s = edge_at(ei, is64, i);
      d = edge_at(ei, is64, (long long)EE + i);
    } else {
      s = d = i - EE;
    }
    if (d < lo || d >= hi || (unsigned)s >= (unsigned)NN) continue;
    int pos = row_ptr[d] + atomicAdd(&cursor[d], 1);
    if ((unsigned)pos < (unsigned)ELL) {
      srcs_sorted[pos] = s;
      float4 as4 = *(const float4*)&asrc[s * 4];
      float4 ad4 = *(const float4*)&adst[d * 4];
      __half hw[4];
      hw[0] = __float2half(__expf(leaky(as4.x + ad4.x)));
      hw[1] = __float2half(__expf(leaky(as4.y + ad4.y)));
      hw[2] = __float2half(__expf(leaky(as4.z + ad4.z)));
      hw[3] = __float2half(__expf(leaky(as4.w + ad4.w)));
      *(uint2*)&w1h[(size_t)pos * 4] = *(uint2*)hw;
    }
  }
}

// ---------------------------------------------------------------------------
// Tiled f32 GEMM, fp16 C output, fused attention-logit epilogue (r8-validated).
// ---------------------------------------------------------------------------

template <int BM, int BN, int BK, int TM, int TN, int AMODE>
__global__ void __launch_bounds__(256) gemm_alpha(const float* __restrict__ A,
                                                  const float* __restrict__ B,
                                                  __half* __restrict__ C,
                                                  const float* __restrict__ a_srcv,
                                                  const float* __restrict__ a_dstv,
                                                  float* __restrict__ asrc_out,
                                                  float* __restrict__ adst_out,
                                                  int M, int N, int K) {
  constexpr int THREADS = (BM / TM) * (BN / TN);
  static_assert(THREADS == 256, "block must be 256 threads");
  static_assert(BM * BK == 1024, "A tile = 4 floats/thread");
  static_assert((TN % 4) == 0 && (TM % 4) == 0, "microtile shape");
  constexpr int BPT = (BK * BN) / THREADS;
  static_assert(BPT == 2 || BPT == 4, "B tile load width");
  __shared__ float As[BK][BM + 4];
  __shared__ float Bs[BK][BN + 4];
  int tid = threadIdx.x;
  int tx = tid % (BN / TN);
  int ty = tid / (BN / TN);
  int row0 = blockIdx.x * BM;
  int col0 = blockIdx.y * BN;
  float acc[TM][TN] = {};
  for (int k0 = 0; k0 < K; k0 += BK) {
    {
      int m = tid / (BK / 4);
      int kk = (tid % (BK / 4)) * 4;
      float4 v = make_float4(0.f, 0.f, 0.f, 0.f);
      int gr = row0 + m;
      if (gr < M) v = *(const float4*)&A[(size_t)gr * K + k0 + kk];
      As[kk + 0][m] = v.x; As[kk + 1][m] = v.y;
      As[kk + 2][m] = v.z; As[kk + 3][m] = v.w;
    }
    if constexpr (BPT == 4) {
      constexpr int T_PER_ROW = BN / 4;
      int kr = tid / T_PER_ROW;
      int nc = (tid % T_PER_ROW) * 4;
      *(float4*)&Bs[kr][nc] = *(const float4*)&B[(size_t)(k0 + kr) * N + col0 + nc];
    } else {
      constexpr int T_PER_ROW = BN / 2;
      int kr = tid / T_PER_ROW;
      int nc = (tid % T_PER_ROW) * 2;
      *(float2*)&Bs[kr][nc] = *(const float2*)&B[(size_t)(k0 + kr) * N + col0 + nc];
    }
    __syncthreads();
    #pragma unroll
    for (int k = 0; k < BK; ++k) {
      float a[TM], b[TN];
      #pragma unroll
      for (int i = 0; i < TM; i += 4)
        *(float4*)&a[i] = *(const float4*)&As[k][ty * TM + i];
      #pragma unroll
      for (int j = 0; j < TN; j += 4)
        *(float4*)&b[j] = *(const float4*)&Bs[k][tx * TN + j];
      #pragma unroll
      for (int i = 0; i < TM; ++i)
        #pragma unroll
        for (int j = 0; j < TN; ++j) acc[i][j] += a[i] * b[j];
    }
    __syncthreads();
  }
  #pragma unroll
  for (int i = 0; i < TM; ++i) {
    int gr = row0 + ty * TM + i;
    if (gr >= M) continue;
    __half tmp[TN];
    #pragma unroll
    for (int j = 0; j < TN; ++j) tmp[j] = __float2half(acc[i][j]);
    if constexpr (TN == 8)
      *(float4*)&C[(size_t)gr * N + col0 + tx * TN] = *(float4*)tmp;
    else
      *(float2*)&C[(size_t)gr * N + col0 + tx * TN] = *(float2*)tmp;
  }
  if (AMODE == 1) {
    int hh = tx >> 2;
    int co = (tx & 3) * TN;
    #pragma unroll
    for (int i = 0; i < TM; ++i) {
      float sA = 0.f, sD = 0.f;
      #pragma unroll
      for (int j = 0; j < TN; ++j) {
        float v = acc[i][j];
        sA += v * a_srcv[hh * 32 + co + j];
        sD += v * a_dstv[hh * 32 + co + j];
      }
      sA += __shfl_xor(sA, 1, 64); sA += __shfl_xor(sA, 2, 64);
      sD += __shfl_xor(sD, 1, 64); sD += __shfl_xor(sD, 2, 64);
      int gr = row0 + ty * TM + i;
      if ((tx & 3) == 0 && gr < M) {
        asrc_out[gr * 4 + hh] = sA;
        adst_out[gr * 4 + hh] = sD;
      }
    }
  } else if (AMODE == 2) {
    #pragma unroll
    for (int i = 0; i < TM; ++i) {
      float sA = 0.f, sD = 0.f;
      #pragma unroll
      for (int j = 0; j < TN; ++j) {
        float v = acc[i][j];
        sA += v * a_srcv[tx * TN + j];
        sD += v * a_dstv[tx * TN + j];
      }
      #pragma unroll
      for (int m = 1; m <= 8; m <<= 1) {
        sA += __shfl_xor(sA, m, 64);
        sD += __shfl_xor(sD, m, 64);
      }
      int gr = row0 + ty * TM + i;
      if (tx == 0 && gr < M) { asrc_out[gr] = sA; adst_out[gr] = sD; }
    }
  }
}

// ---------------------------------------------------------------------------
// Single-pass aggregation, fp16 gathers, precomputed weights (layer 1).
// ---------------------------------------------------------------------------

// Layer 1: one wave per node, TWO edges/iter (half-wave each), unroll 4.
// Inner loop: sequential broadcast loads (srcs[e], w1h[e*4..]) + ONE dependent
// gather (h row). Lane owns 4 channels c0=(lane&31)*4; head myh = c0>>5.
__global__ void __launch_bounds__(256) agg1_fused(
    const __half* __restrict__ h,       // [N,128] fp16
    const int* __restrict__ row_ptr,
    const int* __restrict__ srcs,
    const __half* __restrict__ w1h,     // [ELL,4] fp16 per-edge head weights
    const float* __restrict__ b1,       // [128]
    float* __restrict__ out)            // relu(agg + b1) -> [N,128] fp32
{
  int lane = threadIdx.x & 63;
  int grp = lane >> 5;                  // edge parity of this half-wave
  int cl = lane & 31;
  int c0 = cl * 4;                      // 4 owned channels
  int myh = cl >> 3;                    // head of those channels
  int wid = (blockIdx.x * blockDim.x + threadIdx.x) >> 6;
  int nw = (gridDim.x * blockDim.x) >> 6;
  float4 bb = *(const float4*)&b1[c0];
  for (int n = wid; n < NN; n += nw) {
    int rbeg = row_ptr[n], rend = row_ptr[n + 1];
    float dsum = grp ? 0.f : 1e-16f;
    float a0 = 0.f, a1 = 0.f, a2 = 0.f, a3 = 0.f;
    #pragma unroll 4
    for (int e = rbeg + grp; e < rend; e += 2) {
      int s = srcs[e];
      uint2 wraw = *(const uint2*)&w1h[(size_t)e * 4];        // broadcast 8B
      unsigned wsel = (myh & 2) ? wraw.y : wraw.x;
      __half2 hw = __builtin_bit_cast(__half2, wsel);
      float wgt = (myh & 1) ? __high2float(hw) : __low2float(hw);
      float2 raw = *(const float2*)&h[(size_t)s * 128 + c0];  // dependent gather
      float2 f01 = __half22float2(__builtin_bit_cast(__half2, raw.x));
      float2 f23 = __half22float2(__builtin_bit_cast(__half2, raw.y));
      dsum += wgt;
      a0 += wgt * f01.x; a1 += wgt * f01.y;
      a2 += wgt * f23.x; a3 += wgt * f23.y;
    }
    dsum += __shfl_xor(dsum, 32, 64);
    a0 += __shfl_xor(a0, 32, 64);
    a1 += __shfl_xor(a1, 32, 64);
    a2 += __shfl_xor(a2, 32, 64);
    a3 += __shfl_xor(a3, 32, 64);
    if (lane < 32) {
      float inv = 1.f / dsum;
      float4 o = make_float4(fmaxf(a0 * inv + bb.x, 0.f),
                             fmaxf(a1 * inv + bb.y, 0.f),
                             fmaxf(a2 * inv + bb.z, 0.f),
                             fmaxf(a3 * inv + bb.w, 0.f));
      *(float4*)&out[(size_t)n * 128 + c0] = o;   // fused inter-layer ReLU
    }
  }
}

// Layer 2: one wave per node, FOUR edges/iter (16-lane groups), unroll 4.
__global__ void __launch_bounds__(256) agg2_kernel(
    const __half* __restrict__ h,       // [N,64] fp16
    const int* __restrict__ row_ptr,
    const int* __restrict__ srcs,
    const float* __restrict__ asrc,     // [N]
    const float* __restrict__ adst,     // [N]
    const float* __restrict__ b2,       // [64]
    float* __restrict__ out)            // [N,64] fp32
{
  int lane = threadIdx.x & 63;
  int grp = lane >> 4;
  int cl = lane & 15;
  int c0 = cl * 4;
  int wid = (blockIdx.x * blockDim.x + threadIdx.x) >> 6;
  int nw = (gridDim.x * blockDim.x) >> 6;
  float4 bb = *(const float4*)&b2[c0];
  for (int n = wid; n < NN; n += nw) {
    int rbeg = row_ptr[n], rend = row_ptr[n + 1];
    float ad = adst[n];
    float dsum = (grp == 0) ? 1e-16f : 0.f;
    float a0 = 0.f, a1 = 0.f, a2 = 0.f, a3 = 0.f;
    #pragma unroll 4
    for (int e = rbeg + grp; e < rend; e += 4) {
      int s = srcs[e];
      float wgt = __expf(leaky(asrc[s] + ad));
      float2 raw = *(const float2*)&h[(size_t)s * 64 + c0];
      float2 f01 = __half22float2(__builtin_bit_cast(__half2, raw.x));
      float2 f23 = __half22float2(__builtin_bit_cast(__half2, raw.y));
      dsum += wgt;
      a0 += wgt * f01.x; a1 += wgt * f01.y;
      a2 += wgt * f23.x; a3 += wgt * f23.y;
    }
    #pragma unroll
    for (int m = 16; m <= 32; m <<= 1) {
      dsum += __shfl_xor(dsum, m, 64);
      a0 += __shfl_xor(a0, m, 64);
      a1 += __shfl_xor(a1, m, 64);
      a2 += __shfl_xor(a2, m, 64);
      a3 += __shfl_xor(a3, m, 64);
    }
    if (lane < 16) {
      float inv = 1.f / dsum;
      float4 o = make_float4(a0 * inv + bb.x, a1 * inv + bb.y,
                             a2 * inv + bb.z, a3 * inv + bb.w);
      *(float4*)&out[(size_t)n * 64 + c0] = o;
    }
  }
}

// ---------------------------------------------------------------------------

extern "C" void kernel_launch(void* const* d_in, const int* in_sizes, int n_in,
                              void* d_out, int out_size, void* d_ws, size_t ws_size,
                              hipStream_t stream) {
  const float* x   = (const float*)d_in[0];
  const void*  ei  = d_in[1];               // int32 or int64, probed on device
  const float* W1  = (const float*)d_in[2];
  const float* as1 = (const float*)d_in[3];
  const float* ad1 = (const float*)d_in[4];
  const float* b1  = (const float*)d_in[5];
  const float* W2  = (const float*)d_in[6];
  const float* as2 = (const float*)d_in[7];
  const float* ad2 = (const float*)d_in[8];
  const float* b2  = (const float*)d_in[9];
  float* out = (float*)d_out;

  char* w = (char*)d_ws;
  __half* h1h  = (__half*)w; w += (size_t)NN * 128 * 2;  // layer-1 features fp16
  __half* hb2h = h1h;                                    // alias: dead after agg1
  float* h2    = (float*)w; w += (size_t)NN * 128 * 4;   // relu(GAT1 out) fp32
  float* asrc1 = (float*)w; w += (size_t)NN * 4 * 4;
  float* adst1 = (float*)w; w += (size_t)NN * 4 * 4;
  float* asrc2 = (float*)w; w += (size_t)NN * 4;
  float* adst2 = (float*)w; w += (size_t)NN * 4;
  int* cnt     = (int*)w;   w += (size_t)NN * 4;         // cnt + cursor adjacent:
  int* cursor  = (int*)w;   w += (size_t)NN * 4;         //   zeroed in ONE launch
  int* row_ptr = (int*)w;   w += (size_t)(NN + 1) * 4;
  int* bsum    = (int*)w;   w += 256;
  int* is64    = (int*)w;   w += 256;
  int* srcs_sorted = (int*)w; w += (size_t)ELL * 4;
  __half* w1h  = (__half*)w; w += (size_t)ELL * 4 * 2;   // per-edge head weights

  const int NB = (NN + 1023) / 1024;  // 49
  const int MB128 = (NN + 127) / 128; // 391

  // probe+zero, CSR pointers
  zero_detect_kernel<<<256, 256, 0, stream>>>(cnt, 2 * NN, (const unsigned*)ei, is64);
  count_kernel<<<2048, 256, 0, stream>>>(ei, is64, cnt);
  scan1_kernel<<<NB, 256, 0, stream>>>(cnt, row_ptr, bsum);
  scan2_kernel<<<1, 64, 0, stream>>>(bsum, NB);
  scan3_kernel<<<(NN + 255) / 256, 256, 0, stream>>>(row_ptr, bsum, NB);

  // Layer 1 GEMM first (produces asrc1/adst1 for the weight-fused scatter)
  gemm_alpha<128, 128, 8, 8, 8, 1><<<dim3(MB128, 1), 256, 0, stream>>>(
      x, W1, h1h, as1, ad1, asrc1, adst1, NN, 128, 128);

  // Scatter + layer-1 edge weights
  scatter_kernel<<<2048, 256, 0, stream>>>(ei, is64, row_ptr, cursor, srcs_sorted,
                                           asrc1, adst1, w1h);

  agg1_fused<<<4096, 256, 0, stream>>>(h1h, row_ptr, srcs_sorted, w1h, b1, h2);

  // Layer 2
  gemm_alpha<128, 64, 8, 8, 4, 2><<<dim3(MB128, 1), 256, 0, stream>>>(
      h2, W2, hb2h, as2, ad2, asrc2, adst2, NN, 64, 128);
  agg2_kernel<<<4096, 256, 0, stream>>>(hb2h, row_ptr, srcs_sorted, asrc2, adst2, b2, out);
}